// Round 5
// baseline (390.478 us; speedup 1.0000x reference)
//
#include <hip/hip_runtime.h>

#define B_DIM 8192
#define CELL  1024
#define KA    3328   // A_full row: 1024 x | 1024 htm | 256 spk | 1024 ztm
#define BM    256
#define BN    256
#define BK    64

typedef unsigned short u16;
typedef __attribute__((ext_vector_type(8))) short bf16x8;
typedef __attribute__((ext_vector_type(4))) float f32x4;
typedef __attribute__((ext_vector_type(4))) float fx4;
typedef __attribute__((ext_vector_type(4))) unsigned short u16x4;

__device__ inline u16 f2bf(float f) {
  unsigned u = __float_as_uint(f);
  return (u16)((u + 0x7FFFu + ((u >> 16) & 1u)) >> 16);
}
__device__ inline float rcp_f(float x) { return __builtin_amdgcn_rcpf(x); }
__device__ inline float sigmoid_f(float v) { return rcp_f(1.0f + __expf(-v)); }
__device__ inline float tanh_f(float v) {  // 1 - 2/(e^{2v}+1): +-1 saturation exact
  float e = __expf(2.0f * v);
  return 1.0f - 2.0f * rcp_f(e + 1.0f);
}

// ---------- prep: fp32 -> bf16 concat into A_full (one kernel, 4 regions) ----------
__global__ void cvt_all(const float* __restrict__ x, const float* __restrict__ htm,
                        const float* __restrict__ spk, const float* __restrict__ ztm,
                        u16* __restrict__ dst) {
  int b = blockIdx.x;
  const float* src; int shift, colOff, base;
  if (b < 8192)       { src = x;   shift = 10; colOff = 0;    base = 0; }
  else if (b < 16384) { src = htm; shift = 10; colOff = 1024; base = 8192; }
  else if (b < 18432) { src = spk; shift = 8;  colOff = 2048; base = 16384; }
  else                { src = ztm; shift = 10; colOff = 2304; base = 18432; }
  int i = (b - base) * 256 + threadIdx.x;
  int e = i << 2;
  int row = e >> shift;
  int col = e & ((1 << shift) - 1);
  float4 v = *reinterpret_cast<const float4*>(src + e);
  u16x4 o;
  o[0] = f2bf(v.x); o[1] = f2bf(v.y); o[2] = f2bf(v.z); o[3] = f2bf(v.w);
  *reinterpret_cast<u16x4*>(dst + (size_t)row * KA + colOff + col) = o;
}

// ---------- prep: transpose weights [K][N] fp32 -> [Npacked][KT] bf16 ----------
// packed=1: p = (c>>4)*64 + gate*16 + (c&15), where src col j = gate*1024 + c
__global__ void wtrans(const float* __restrict__ src, int N,
                       u16* __restrict__ dst, int KT, int koff, int packed) {
  __shared__ float tile[32][33];
  int n0 = blockIdx.x * 32, k0 = blockIdx.y * 32;
  int tx = threadIdx.x, ty = threadIdx.y;  // 32x8
#pragma unroll
  for (int j = 0; j < 4; ++j)
    tile[ty + j * 8][tx] = src[(size_t)(k0 + ty + j * 8) * N + n0 + tx];
  __syncthreads();
#pragma unroll
  for (int j = 0; j < 4; ++j) {
    int jj = n0 + ty + j * 8;
    int p = packed ? (((jj & 1023) >> 4) << 6) + ((jj >> 10) << 4) + (jj & 15) : jj;
    dst[(size_t)p * KT + koff + k0 + tx] = f2bf(tile[tx][ty + j * 8]);
  }
}

// ---------- fused GEMM + LSTM ----------
__device__ __forceinline__ void gload_lds16(const void* g, void* l) {
  __builtin_amdgcn_global_load_lds((const __attribute__((address_space(1))) void*)g,
                                   (__attribute__((address_space(3))) void*)l,
                                   16, 0, 0);
}

// stage one half (128 rows x 64 k): LDS dest linear, global source slot
// pre-XOR-swizzled (rule 21) so ds_read-with-XOR sees correct data.
__device__ __forceinline__ void stage_half(const u16* __restrict__ g0, int ldk,
                                           u16* ldsTile, int half, int kt,
                                           int wave, int lane) {
#pragma unroll
  for (int k2 = 0; k2 < 2; ++k2) {
    const int r0 = half * 128 + k2 * 64 + wave * 8;
    const int r = r0 + (lane >> 3);
    const int slot = (lane & 7) ^ (lane >> 3);
    const u16* g = g0 + (size_t)r * ldk + kt * 64 + slot * 8;
    gload_lds16((const void*)g, (void*)(ldsTile + r0 * 64));
  }
}

#define LD_A(ASP, QP)                                                              \
  aq[0][0] = *reinterpret_cast<const bf16x8*>((ASP) + aBase0 + (2 * (QP)) * 1024);     \
  aq[0][1] = *reinterpret_cast<const bf16x8*>((ASP) + aBase1 + (2 * (QP)) * 1024);     \
  aq[1][0] = *reinterpret_cast<const bf16x8*>((ASP) + aBase0 + (2 * (QP) + 1) * 1024); \
  aq[1][1] = *reinterpret_cast<const bf16x8*>((ASP) + aBase1 + (2 * (QP) + 1) * 1024);

#define LD_B(BSP)                                                                  \
  _Pragma("unroll")                                                                \
  for (int n = 0; n < 4; ++n) {                                                    \
    br[n][0] = *reinterpret_cast<const bf16x8*>((BSP) + bBase0 + n * 1024);        \
    br[n][1] = *reinterpret_cast<const bf16x8*>((BSP) + bBase1 + n * 1024);        \
  }

#define MFMA_PH(QP)                                                                \
  __builtin_amdgcn_s_setprio(1);                                                   \
  _Pragma("unroll")                                                                \
  for (int q = 0; q < 2; ++q) {                                                    \
    _Pragma("unroll")                                                              \
    for (int n = 0; n < 4; ++n) {                                                  \
      acc[2 * (QP) + q][n] = __builtin_amdgcn_mfma_f32_16x16x32_bf16(              \
          aq[q][0], br[n][0], acc[2 * (QP) + q][n], 0, 0, 0);                      \
      acc[2 * (QP) + q][n] = __builtin_amdgcn_mfma_f32_16x16x32_bf16(              \
          aq[q][1], br[n][1], acc[2 * (QP) + q][n], 0, 0, 0);                      \
    }                                                                              \
  }                                                                                \
  __builtin_amdgcn_s_setprio(0);

#define ENTRY_BAR                                                                  \
  __builtin_amdgcn_sched_barrier(0);                                               \
  __builtin_amdgcn_s_barrier();                                                    \
  asm volatile("s_waitcnt lgkmcnt(0)" ::: "memory");                               \
  __builtin_amdgcn_sched_barrier(0);

#define EXIT_BAR __builtin_amdgcn_s_barrier();

// one gate K-tile: read (Acur,Bcur), deep-prefetch tile t+2 into (An2,Bn2).
// vmcnt(8): A(t+1),B(t+1) retired; A(t+2),B(t+2) (8 newest) stay in flight.
#define TILE6(Acur, Bcur, An2, Bn2, TT)                                            \
  {                                                                                \
    const int t2 = (TT) + 2;                                                       \
    const bool nl = (t2 < 36);                                                     \
    LD_B(Bcur)                                                                     \
    LD_A(Acur, 0)                                                                  \
    if (nl) stage_half(Ag, KA, An2, 0, t2, wave, lane);                            \
    ENTRY_BAR MFMA_PH(0) EXIT_BAR                                                  \
    LD_A(Acur, 1)                                                                  \
    if (nl) stage_half(Ag, KA, An2, 1, t2, wave, lane);                            \
    ENTRY_BAR MFMA_PH(1) EXIT_BAR                                                  \
    LD_A(Acur, 2)                                                                  \
    if (nl) stage_half(Bg, 2304, Bn2, 0, t2, wave, lane);                          \
    ENTRY_BAR MFMA_PH(2) EXIT_BAR                                                  \
    LD_A(Acur, 3)                                                                  \
    if (nl) stage_half(Bg, 2304, Bn2, 1, t2, wave, lane);                          \
    ENTRY_BAR MFMA_PH(3)                                                           \
    if (nl) { asm volatile("s_waitcnt vmcnt(8)" ::: "memory"); }                   \
    else    { asm volatile("s_waitcnt vmcnt(0)" ::: "memory"); }                   \
    EXIT_BAR                                                                       \
  }

__global__ __launch_bounds__(512, 2) void gemm_fused(
    const u16* __restrict__ Afull, const u16* __restrict__ WT4p,
    const u16* __restrict__ VwT, const float* __restrict__ ctm,
    const float* __restrict__ Wb, const float* __restrict__ Ub,
    const float* __restrict__ Sb, const float* __restrict__ Vb,
    float* __restrict__ outC, float* __restrict__ outH) {
  __shared__ u16 As[3][BM * BK];   // 3-deep A (deep prefetch)
  __shared__ u16 Bs[2][BN * BK];   // 2-deep B (L2-resident panel)
  const int tid = threadIdx.x;
  const int wave = tid >> 6, lane = tid & 63;
  const int wm = wave >> 2, wn = wave & 3;       // 2 x 4 wave grid
  const int lrow = lane & 15, khi = lane >> 4;

  // T1: bijective XCD swizzle (512 % 8 == 0); XCD keeps its 2 B-panels L2-resident.
  const int bid = blockIdx.x;
  const int tilei = ((bid & 7) << 6) | (bid >> 3);
  const int nb = tilei >> 5, mb = tilei & 31;
  const int m0 = mb * 256;
  const u16* Ag = Afull + (size_t)m0 * KA;            // gates A: cols 0..2303
  const u16* Ah = Afull + (size_t)m0 * KA + 2304;     // hybrid A: ztm cols
  const u16* Bg = WT4p + (size_t)(nb * 256) * 2304;   // packed gate weights

  const int sw = lane & 7;
  const int swz0 = ((0 + khi) ^ sw) * 8;
  const int swz1 = ((4 + khi) ^ sw) * 8;
  const int aBase0 = (wm * 128 + lrow) * 64 + swz0;
  const int aBase1 = (wm * 128 + lrow) * 64 + swz1;
  const int bBase0 = (wn * 64 + lrow) * 64 + swz0;
  const int bBase1 = (wn * 64 + lrow) * 64 + swz1;

  // this lane's output column and its VwT row (hybrid B read direct from global)
  const int co = nb * 64 + wn * 16 + lrow;
  const u16* HgRow = VwT + (size_t)co * 1024;

  f32x4 acc[8][4];
#pragma unroll
  for (int m2 = 0; m2 < 8; ++m2)
#pragma unroll
    for (int n2 = 0; n2 < 4; ++n2) acc[m2][n2] = (f32x4){0.f, 0.f, 0.f, 0.f};
  bf16x8 aq[2][2], br[4][2];
  u16* As0 = As[0]; u16* As1 = As[1]; u16* As2 = As[2];
  u16* Bs0 = Bs[0]; u16* Bs1 = Bs[1];

  // ======== gate GEMM: K=2304, 36 k-tiles, 8-phase + 3-deep A prefetch ========
  // prologue: A(0),B(0),A(1),B(1); wait A(0),B(0) (8 newest in flight)
  stage_half(Ag, KA, As0, 0, 0, wave, lane);
  stage_half(Ag, KA, As0, 1, 0, wave, lane);
  stage_half(Bg, 2304, Bs0, 0, 0, wave, lane);
  stage_half(Bg, 2304, Bs0, 1, 0, wave, lane);
  stage_half(Ag, KA, As1, 0, 1, wave, lane);
  stage_half(Ag, KA, As1, 1, 1, wave, lane);
  stage_half(Bg, 2304, Bs1, 0, 1, wave, lane);
  stage_half(Bg, 2304, Bs1, 1, 1, wave, lane);
  asm volatile("s_waitcnt vmcnt(8)" ::: "memory");
  __builtin_amdgcn_s_barrier();

#pragma unroll 1
  for (int tb = 0; tb < 36; tb += 6) {
    TILE6(As0, Bs0, As2, Bs0, tb + 0)
    TILE6(As1, Bs1, As0, Bs1, tb + 1)
    TILE6(As2, Bs0, As1, Bs0, tb + 2)
    TILE6(As0, Bs1, As2, Bs1, tb + 3)
    TILE6(As1, Bs0, As0, Bs0, tb + 4)
    TILE6(As2, Bs1, As1, Bs1, tb + 5)
  }

  // ======== hybrid GEMM: ztm @ Vw (K=1024), round-1-style 1-barrier dbuf ========
  f32x4 acch[8];
#pragma unroll
  for (int m2 = 0; m2 < 8; ++m2) acch[m2] = (f32x4){0.f, 0.f, 0.f, 0.f};

  stage_half(Ah, KA, As0, 0, 0, wave, lane);
  stage_half(Ah, KA, As0, 1, 0, wave, lane);

#pragma unroll 1
  for (int kt = 0; kt < 16; ++kt) {
    __syncthreads();  // compiler drains vmcnt/lgkm: As[kt&1] staged & prior reads retired
    u16* AsP = (kt & 1) ? As1 : As0;
    if (kt + 1 < 16) {
      u16* AsN = (kt & 1) ? As0 : As1;
      stage_half(Ah, KA, AsN, 0, kt + 1, wave, lane);
      stage_half(Ah, KA, AsN, 1, kt + 1, wave, lane);
    }
    bf16x8 bh0 = *reinterpret_cast<const bf16x8*>(HgRow + kt * 64 + khi * 8);
    bf16x8 bh1 = *reinterpret_cast<const bf16x8*>(HgRow + kt * 64 + 32 + khi * 8);
#pragma unroll
    for (int qp = 0; qp < 4; ++qp) {
      LD_A(AsP, qp)
      acch[2 * qp]     = __builtin_amdgcn_mfma_f32_16x16x32_bf16(aq[0][0], bh0, acch[2 * qp], 0, 0, 0);
      acch[2 * qp]     = __builtin_amdgcn_mfma_f32_16x16x32_bf16(aq[0][1], bh1, acch[2 * qp], 0, 0, 0);
      acch[2 * qp + 1] = __builtin_amdgcn_mfma_f32_16x16x32_bf16(aq[1][0], bh0, acch[2 * qp + 1], 0, 0, 0);
      acch[2 * qp + 1] = __builtin_amdgcn_mfma_f32_16x16x32_bf16(aq[1][1], bh1, acch[2 * qp + 1], 0, 0, 0);
    }
  }

  // ======== fused LSTM epilogue (per-wave, fp32, direct to d_out) ========
  const float bf = Wb[co] + Ub[co] + Sb[co];
  const float bi = Wb[1024 + co] + Ub[1024 + co] + Sb[1024 + co];
  const float bo = Wb[2048 + co] + Ub[2048 + co] + Sb[2048 + co];
  const float bc = Wb[3072 + co] + Ub[3072 + co] + Sb[3072 + co];
  const float bv = Vb[co];
#pragma unroll
  for (int mf = 0; mf < 8; ++mf) {
    const int r0 = m0 + wm * 128 + mf * 16 + khi * 4;
#pragma unroll
    for (int j = 0; j < 4; ++j) {
      const size_t idx = (size_t)(r0 + j) * CELL + co;
      float f_ = sigmoid_f(acc[mf][0][j] + bf);
      float i_ = sigmoid_f(acc[mf][1][j] + bi);
      float o_ = sigmoid_f(acc[mf][2][j] + bo);
      float g_ = tanh_f(acc[mf][3][j] + bc);
      float fh = sigmoid_f(acch[mf][j] + bv);
      float ct = ctm[idx];
      float cc = (f_ + fh) * ct + i_ * g_;
      outC[idx] = cc;
      outH[idx] = tanh_f(cc) * o_;
    }
  }
}

extern "C" void kernel_launch(void* const* d_in, const int* in_sizes, int n_in,
                              void* d_out, int out_size, void* d_ws, size_t ws_size,
                              hipStream_t stream) {
  const float* x   = (const float*)d_in[0];
  const float* ctm = (const float*)d_in[1];
  const float* htm = (const float*)d_in[2];
  const float* ztm = (const float*)d_in[3];
  const float* spk = (const float*)d_in[4];
  const float* Ww  = (const float*)d_in[5];
  const float* Wb  = (const float*)d_in[6];
  const float* Uw  = (const float*)d_in[7];
  const float* Ub  = (const float*)d_in[8];
  const float* Vw  = (const float*)d_in[9];
  const float* Vb  = (const float*)d_in[10];
  const float* Sw  = (const float*)d_in[11];
  const float* Sb  = (const float*)d_in[12];

  // workspace (bf16): A_full | WT4 packed | VwT   (~76 MB)
  u16* Afull = (u16*)d_ws;
  u16* WT4p  = Afull + (size_t)B_DIM * KA;
  u16* VwT   = WT4p + (size_t)4096 * 2304;
  float* outC = (float*)d_out;
  float* outH = outC + (size_t)B_DIM * CELL;

  cvt_all<<<26624, 256, 0, stream>>>(x, htm, spk, ztm, Afull);

  wtrans<<<dim3(128, 32), dim3(32, 8), 0, stream>>>(Ww, 4096, WT4p, 2304, 0,    1);
  wtrans<<<dim3(128, 32), dim3(32, 8), 0, stream>>>(Uw, 4096, WT4p, 2304, 1024, 1);
  wtrans<<<dim3(128, 8),  dim3(32, 8), 0, stream>>>(Sw, 4096, WT4p, 2304, 2048, 1);
  wtrans<<<dim3(32, 32),  dim3(32, 8), 0, stream>>>(Vw, 1024, VwT,  1024, 0,    0);

  gemm_fused<<<512, 512, 0, stream>>>(Afull, WT4p, VwT, ctm, Wb, Ub, Sb, Vb, outC, outH);
}

// Round 6
// 254.220 us; speedup vs baseline: 1.5360x; 1.5360x over previous
//
#include <hip/hip_runtime.h>

#define B_DIM 8192
#define CELL  1024
#define KA    3328   // A_full row: 1024 x | 1024 htm | 256 spk | 1024 ztm
#define BM    256
#define BN    256
#define BK    64

typedef unsigned short u16;
typedef __attribute__((ext_vector_type(8))) short bf16x8;
typedef __attribute__((ext_vector_type(4))) float f32x4;
typedef __attribute__((ext_vector_type(4))) float fx4;
typedef __attribute__((ext_vector_type(4))) unsigned short u16x4;

__device__ inline u16 f2bf(float f) {
  unsigned u = __float_as_uint(f);
  return (u16)((u + 0x7FFFu + ((u >> 16) & 1u)) >> 16);
}
__device__ inline float rcp_f(float x) { return __builtin_amdgcn_rcpf(x); }
__device__ inline float sigmoid_f(float v) { return rcp_f(1.0f + __expf(-v)); }
__device__ inline float tanh_f(float v) {  // 1 - 2/(e^{2v}+1)
  float e = __expf(2.0f * v);
  return 1.0f - 2.0f * rcp_f(e + 1.0f);
}

// ---------- prep: fp32 -> bf16 concat into A_full (one kernel, 4 regions) ----------
__global__ void cvt_all(const float* __restrict__ x, const float* __restrict__ htm,
                        const float* __restrict__ spk, const float* __restrict__ ztm,
                        u16* __restrict__ dst) {
  int b = blockIdx.x;
  const float* src; int shift, colOff, base;
  if (b < 8192)       { src = x;   shift = 10; colOff = 0;    base = 0; }
  else if (b < 16384) { src = htm; shift = 10; colOff = 1024; base = 8192; }
  else if (b < 18432) { src = spk; shift = 8;  colOff = 2048; base = 16384; }
  else                { src = ztm; shift = 10; colOff = 2304; base = 18432; }
  int i = (b - base) * 256 + threadIdx.x;
  int e = i << 2;
  int row = e >> shift;
  int col = e & ((1 << shift) - 1);
  float4 v = *reinterpret_cast<const float4*>(src + e);
  u16x4 o;
  o[0] = f2bf(v.x); o[1] = f2bf(v.y); o[2] = f2bf(v.z); o[3] = f2bf(v.w);
  *reinterpret_cast<u16x4*>(dst + (size_t)row * KA + colOff + col) = o;
}

// ---------- prep: transpose weights [K][N] fp32 -> [Npacked][KT] bf16 ----------
// packed=1: p = (c>>4)*64 + gate*16 + (c&15), where src col j = gate*1024 + c
__global__ void wtrans(const float* __restrict__ src, int N,
                       u16* __restrict__ dst, int KT, int koff, int packed) {
  __shared__ float tile[32][33];
  int n0 = blockIdx.x * 32, k0 = blockIdx.y * 32;
  int tx = threadIdx.x, ty = threadIdx.y;  // 32x8
#pragma unroll
  for (int j = 0; j < 4; ++j)
    tile[ty + j * 8][tx] = src[(size_t)(k0 + ty + j * 8) * N + n0 + tx];
  __syncthreads();
#pragma unroll
  for (int j = 0; j < 4; ++j) {
    int jj = n0 + ty + j * 8;
    int p = packed ? (((jj & 1023) >> 4) << 6) + ((jj >> 10) << 4) + (jj & 15) : jj;
    dst[(size_t)p * KT + koff + k0 + tx] = f2bf(tile[tx][ty + j * 8]);
  }
}

// ---------- fused GEMM + LSTM ----------
__device__ __forceinline__ void gload_lds16(const void* g, void* l) {
  __builtin_amdgcn_global_load_lds((const __attribute__((address_space(1))) void*)g,
                                   (__attribute__((address_space(3))) void*)l,
                                   16, 0, 0);
}

// stage one half (128 rows x 64 k): LDS dest linear, global source slot
// pre-XOR-swizzled (rule 21) so ds_read-with-XOR sees correct data.
__device__ __forceinline__ void stage_half(const u16* __restrict__ g0, int ldk,
                                           u16* ldsTile, int half, int kt,
                                           int wave, int lane) {
#pragma unroll
  for (int k2 = 0; k2 < 2; ++k2) {
    const int r0 = half * 128 + k2 * 64 + wave * 8;
    const int r = r0 + (lane >> 3);
    const int slot = (lane & 7) ^ (lane >> 3);
    const u16* g = g0 + (size_t)r * ldk + kt * 64 + slot * 8;
    gload_lds16((const void*)g, (void*)(ldsTile + r0 * 64));
  }
}

#define LD_A(ASP, QP)                                                              \
  aq[0][0] = *reinterpret_cast<const bf16x8*>((ASP) + aBase0 + (2 * (QP)) * 1024);     \
  aq[0][1] = *reinterpret_cast<const bf16x8*>((ASP) + aBase1 + (2 * (QP)) * 1024);     \
  aq[1][0] = *reinterpret_cast<const bf16x8*>((ASP) + aBase0 + (2 * (QP) + 1) * 1024); \
  aq[1][1] = *reinterpret_cast<const bf16x8*>((ASP) + aBase1 + (2 * (QP) + 1) * 1024);

#define LD_B(BSP)                                                                  \
  _Pragma("unroll")                                                                \
  for (int n = 0; n < 4; ++n) {                                                    \
    br[n][0] = *reinterpret_cast<const bf16x8*>((BSP) + bBase0 + n * 1024);        \
    br[n][1] = *reinterpret_cast<const bf16x8*>((BSP) + bBase1 + n * 1024);        \
  }

#define MFMA_PH(QP)                                                                \
  __builtin_amdgcn_s_setprio(1);                                                   \
  _Pragma("unroll")                                                                \
  for (int q = 0; q < 2; ++q) {                                                    \
    _Pragma("unroll")                                                              \
    for (int n = 0; n < 4; ++n) {                                                  \
      acc[2 * (QP) + q][n] = __builtin_amdgcn_mfma_f32_16x16x32_bf16(              \
          aq[q][0], br[n][0], acc[2 * (QP) + q][n], 0, 0, 0);                      \
      acc[2 * (QP) + q][n] = __builtin_amdgcn_mfma_f32_16x16x32_bf16(              \
          aq[q][1], br[n][1], acc[2 * (QP) + q][n], 0, 0, 0);                      \
    }                                                                              \
  }                                                                                \
  __builtin_amdgcn_s_setprio(0);

#define ENTRY_BAR                                                                  \
  __builtin_amdgcn_sched_barrier(0);                                               \
  __builtin_amdgcn_s_barrier();                                                    \
  asm volatile("s_waitcnt lgkmcnt(0)" ::: "memory");                               \
  __builtin_amdgcn_sched_barrier(0);

#define EXIT_BAR __builtin_amdgcn_s_barrier();

__global__ __launch_bounds__(512, 2) void gemm_fused(
    const u16* __restrict__ Afull, const u16* __restrict__ WT4p,
    const u16* __restrict__ VwT, const float* __restrict__ ctm,
    const float* __restrict__ Wb, const float* __restrict__ Ub,
    const float* __restrict__ Sb, const float* __restrict__ Vb,
    float* __restrict__ outC, float* __restrict__ outH) {
  __shared__ u16 As[2][BM * BK];
  __shared__ u16 Bs[2][BN * BK];
  const int tid = threadIdx.x;
  const int wave = tid >> 6, lane = tid & 63;
  const int wm = wave >> 2, wn = wave & 3;       // 2 x 4 wave grid
  const int lrow = lane & 15, khi = lane >> 4;

  // T1: bijective XCD swizzle (512 % 8 == 0).
  const int bid = blockIdx.x;
  const int tilei = ((bid & 7) << 6) | (bid >> 3);
  const int nb = tilei >> 5, mb = tilei & 31;
  const int m0 = mb * 256;
  const u16* Ag = Afull + (size_t)m0 * KA;            // gates A: cols 0..2303
  const u16* Ah = Afull + (size_t)m0 * KA + 2304;     // hybrid A: ztm cols
  const u16* Bg = WT4p + (size_t)(nb * 256) * 2304;   // packed gate weights

  const int sw = lane & 7;
  const int swz0 = ((0 + khi) ^ sw) * 8;
  const int swz1 = ((4 + khi) ^ sw) * 8;
  const int aBase0 = (wm * 128 + lrow) * 64 + swz0;
  const int aBase1 = (wm * 128 + lrow) * 64 + swz1;
  const int bBase0 = (wn * 64 + lrow) * 64 + swz0;
  const int bBase1 = (wn * 64 + lrow) * 64 + swz1;

  // this lane's output column and its VwT row (hybrid B read direct from global)
  const int co = nb * 64 + wn * 16 + lrow;
  const u16* HgRow = VwT + (size_t)co * 1024;

  f32x4 acc[8][4];
#pragma unroll
  for (int m2 = 0; m2 < 8; ++m2)
#pragma unroll
    for (int n2 = 0; n2 < 4; ++n2) acc[m2][n2] = (f32x4){0.f, 0.f, 0.f, 0.f};
  bf16x8 aq[2][2], br[4][2];
  u16* As0 = As[0]; u16* As1 = As[1]; u16* Bs0 = Bs[0]; u16* Bs1 = Bs[1];

  // ======== gate GEMM: K=2304, 36 k-tiles, verified 8-phase loop (round-4) ========
  stage_half(Ag, KA, As0, 0, 0, wave, lane);
  stage_half(Ag, KA, As0, 1, 0, wave, lane);
  stage_half(Bg, 2304, Bs0, 0, 0, wave, lane);
  stage_half(Bg, 2304, Bs0, 1, 0, wave, lane);
  stage_half(Bg, 2304, Bs1, 0, 1, wave, lane);
  stage_half(Bg, 2304, Bs1, 1, 1, wave, lane);
  asm volatile("s_waitcnt vmcnt(4)" ::: "memory");
  __builtin_amdgcn_s_barrier();

#pragma unroll 1
  for (int it = 0; it < 18; ++it) {
    const int t = it * 2;
    const bool nl = (t + 2 < 36);
    LD_B(Bs0)
    LD_A(As0, 0)
    stage_half(Ag, KA, As1, 0, t + 1, wave, lane);
    ENTRY_BAR MFMA_PH(0) EXIT_BAR

    LD_A(As0, 1)
    stage_half(Ag, KA, As1, 1, t + 1, wave, lane);
    ENTRY_BAR MFMA_PH(1) EXIT_BAR

    LD_A(As0, 2)
    if (nl) stage_half(Bg, 2304, Bs0, 0, t + 2, wave, lane);
    ENTRY_BAR MFMA_PH(2) EXIT_BAR

    LD_A(As0, 3)
    if (nl) stage_half(Bg, 2304, Bs0, 1, t + 2, wave, lane);
    ENTRY_BAR MFMA_PH(3)
    if (nl) { asm volatile("s_waitcnt vmcnt(4)" ::: "memory"); }
    else    { asm volatile("s_waitcnt vmcnt(0)" ::: "memory"); }
    EXIT_BAR

    LD_B(Bs1)
    LD_A(As1, 0)
    if (nl) stage_half(Ag, KA, As0, 0, t + 2, wave, lane);
    ENTRY_BAR MFMA_PH(0) EXIT_BAR

    LD_A(As1, 1)
    if (nl) stage_half(Ag, KA, As0, 1, t + 2, wave, lane);
    ENTRY_BAR MFMA_PH(1) EXIT_BAR

    LD_A(As1, 2)
    if (nl) stage_half(Bg, 2304, Bs1, 0, t + 3, wave, lane);
    ENTRY_BAR MFMA_PH(2) EXIT_BAR

    LD_A(As1, 3)
    if (nl) stage_half(Bg, 2304, Bs1, 1, t + 3, wave, lane);
    ENTRY_BAR MFMA_PH(3)
    if (nl) { asm volatile("s_waitcnt vmcnt(4)" ::: "memory"); }
    else    { asm volatile("s_waitcnt vmcnt(0)" ::: "memory"); }
    EXIT_BAR
  }

  // ======== hybrid GEMM: ztm @ Vw (K=1024), 1-barrier dbuf (round-5 verified) ========
  f32x4 acch[8];
#pragma unroll
  for (int m2 = 0; m2 < 8; ++m2) acch[m2] = (f32x4){0.f, 0.f, 0.f, 0.f};

  stage_half(Ah, KA, As0, 0, 0, wave, lane);
  stage_half(Ah, KA, As0, 1, 0, wave, lane);

#pragma unroll 1
  for (int kt = 0; kt < 16; ++kt) {
    __syncthreads();  // compiler drains vmcnt/lgkm: As[kt&1] staged & prior reads retired
    u16* AsP = (kt & 1) ? As1 : As0;
    if (kt + 1 < 16) {
      u16* AsN = (kt & 1) ? As0 : As1;
      stage_half(Ah, KA, AsN, 0, kt + 1, wave, lane);
      stage_half(Ah, KA, AsN, 1, kt + 1, wave, lane);
    }
    bf16x8 bh0 = *reinterpret_cast<const bf16x8*>(HgRow + kt * 64 + khi * 8);
    bf16x8 bh1 = *reinterpret_cast<const bf16x8*>(HgRow + kt * 64 + 32 + khi * 8);
#pragma unroll
    for (int qp = 0; qp < 4; ++qp) {
      LD_A(AsP, qp)
      acch[2 * qp]     = __builtin_amdgcn_mfma_f32_16x16x32_bf16(aq[0][0], bh0, acch[2 * qp], 0, 0, 0);
      acch[2 * qp]     = __builtin_amdgcn_mfma_f32_16x16x32_bf16(aq[0][1], bh1, acch[2 * qp], 0, 0, 0);
      acch[2 * qp + 1] = __builtin_amdgcn_mfma_f32_16x16x32_bf16(aq[1][0], bh0, acch[2 * qp + 1], 0, 0, 0);
      acch[2 * qp + 1] = __builtin_amdgcn_mfma_f32_16x16x32_bf16(aq[1][1], bh1, acch[2 * qp + 1], 0, 0, 0);
    }
  }

  // ======== fused LSTM epilogue (per-wave, fp32, direct to d_out) ========
  const float bf = Wb[co] + Ub[co] + Sb[co];
  const float bi = Wb[1024 + co] + Ub[1024 + co] + Sb[1024 + co];
  const float bo = Wb[2048 + co] + Ub[2048 + co] + Sb[2048 + co];
  const float bc = Wb[3072 + co] + Ub[3072 + co] + Sb[3072 + co];
  const float bv = Vb[co];
#pragma unroll
  for (int mf = 0; mf < 8; ++mf) {
    const int r0 = m0 + wm * 128 + mf * 16 + khi * 4;
#pragma unroll
    for (int j = 0; j < 4; ++j) {
      const size_t idx = (size_t)(r0 + j) * CELL + co;
      float f_ = sigmoid_f(acc[mf][0][j] + bf);
      float i_ = sigmoid_f(acc[mf][1][j] + bi);
      float o_ = sigmoid_f(acc[mf][2][j] + bo);
      float g_ = tanh_f(acc[mf][3][j] + bc);
      float fh = sigmoid_f(acch[mf][j] + bv);
      float ct = ctm[idx];
      float cc = (f_ + fh) * ct + i_ * g_;
      outC[idx] = cc;
      outH[idx] = tanh_f(cc) * o_;
    }
  }
}

extern "C" void kernel_launch(void* const* d_in, const int* in_sizes, int n_in,
                              void* d_out, int out_size, void* d_ws, size_t ws_size,
                              hipStream_t stream) {
  const float* x   = (const float*)d_in[0];
  const float* ctm = (const float*)d_in[1];
  const float* htm = (const float*)d_in[2];
  const float* ztm = (const float*)d_in[3];
  const float* spk = (const float*)d_in[4];
  const float* Ww  = (const float*)d_in[5];
  const float* Wb  = (const float*)d_in[6];
  const float* Uw  = (const float*)d_in[7];
  const float* Ub  = (const float*)d_in[8];
  const float* Vw  = (const float*)d_in[9];
  const float* Vb  = (const float*)d_in[10];
  const float* Sw  = (const float*)d_in[11];
  const float* Sb  = (const float*)d_in[12];

  // workspace (bf16): A_full | WT4 packed | VwT   (~76 MB)
  u16* Afull = (u16*)d_ws;
  u16* WT4p  = Afull + (size_t)B_DIM * KA;
  u16* VwT   = WT4p + (size_t)4096 * 2304;
  float* outC = (float*)d_out;
  float* outH = outC + (size_t)B_DIM * CELL;

  cvt_all<<<26624, 256, 0, stream>>>(x, htm, spk, ztm, Afull);

  wtrans<<<dim3(128, 32), dim3(32, 8), 0, stream>>>(Ww, 4096, WT4p, 2304, 0,    1);
  wtrans<<<dim3(128, 32), dim3(32, 8), 0, stream>>>(Uw, 4096, WT4p, 2304, 1024, 1);
  wtrans<<<dim3(128, 8),  dim3(32, 8), 0, stream>>>(Sw, 4096, WT4p, 2304, 2048, 1);
  wtrans<<<dim3(32, 32),  dim3(32, 8), 0, stream>>>(Vw, 1024, VwT,  1024, 0,    0);

  gemm_fused<<<512, 512, 0, stream>>>(Afull, WT4p, VwT, ctm, Wb, Ub, Sb, Vb, outC, outH);
}